// Round 1
// baseline (1158.607 us; speedup 1.0000x reference)
//
#include <hip/hip_runtime.h>

constexpr int D = 1024;   // d_model
constexpr int S = 1024;   // seq len
constexpr int NB = 4;     // batch
constexpr int NH = 16;    // heads
constexpr int DK = 64;    // head dim
constexpr float THRESH = 0.019f;
constexpr float NEG_INF = -1e9f;
constexpr int ROWS = 8;   // q-rows per attention block

__device__ __forceinline__ float wave_max(float v) {
#pragma unroll
    for (int off = 32; off >= 1; off >>= 1)
        v = fmaxf(v, __shfl_xor(v, off, 64));
    return v;
}
__device__ __forceinline__ float wave_sum(float v) {
#pragma unroll
    for (int off = 32; off >= 1; off >>= 1)
        v += __shfl_xor(v, off, 64);
    return v;
}

// Y[m][n] = sum_k X[m][k] * W[n][k] + bias[n], written head-split to out[B,H,S,DK]
__global__ __launch_bounds__(256) void proj_kernel(
    const float* __restrict__ Qi, const float* __restrict__ Ki, const float* __restrict__ Vi,
    const float* __restrict__ Wq, const float* __restrict__ bq,
    const float* __restrict__ Wk, const float* __restrict__ bk,
    const float* __restrict__ Wv, const float* __restrict__ bv,
    float* __restrict__ qo, float* __restrict__ ko, float* __restrict__ vo)
{
    const int pz = blockIdx.z;
    const float* __restrict__ X    = (pz == 0) ? Qi : (pz == 1) ? Ki : Vi;
    const float* __restrict__ W    = (pz == 0) ? Wq : (pz == 1) ? Wk : Wv;
    const float* __restrict__ bias = (pz == 0) ? bq : (pz == 1) ? bk : bv;
    float* __restrict__ out        = (pz == 0) ? qo : (pz == 1) ? ko : vo;

    __shared__ __align__(16) float As[16][68];
    __shared__ __align__(16) float Bs[16][68];

    const int t  = threadIdx.x;
    const int tx = t & 15;
    const int ty = t >> 4;
    const int m0 = blockIdx.y * 64;
    const int n0 = blockIdx.x * 64;
    const int lr = t >> 2;          // 0..63 tile row
    const int lk = (t & 3) << 2;    // 0,4,8,12

    float acc[4][4] = {};

    for (int k0 = 0; k0 < D; k0 += 16) {
        float4 av  = *(const float4*)&X[(size_t)(m0 + lr) * D + k0 + lk];
        float4 bv4 = *(const float4*)&W[(size_t)(n0 + lr) * D + k0 + lk];
        As[lk + 0][lr] = av.x;  As[lk + 1][lr] = av.y;  As[lk + 2][lr] = av.z;  As[lk + 3][lr] = av.w;
        Bs[lk + 0][lr] = bv4.x; Bs[lk + 1][lr] = bv4.y; Bs[lk + 2][lr] = bv4.z; Bs[lk + 3][lr] = bv4.w;
        __syncthreads();
#pragma unroll
        for (int kk = 0; kk < 16; ++kk) {
            float4 a  = *(const float4*)&As[kk][ty << 2];
            float4 bb = *(const float4*)&Bs[kk][tx << 2];
            float a4[4] = {a.x, a.y, a.z, a.w};
            float b4[4] = {bb.x, bb.y, bb.z, bb.w};
#pragma unroll
            for (int i = 0; i < 4; ++i)
#pragma unroll
                for (int j = 0; j < 4; ++j)
                    acc[i][j] += a4[i] * b4[j];
        }
        __syncthreads();
    }

    const int h = n0 >> 6;  // head is constant per block (n-tile = 64 = DK)
#pragma unroll
    for (int i = 0; i < 4; ++i) {
        const int m  = m0 + (ty << 2) + i;
        const int bb = m >> 10;
        const int sr = m & 1023;
#pragma unroll
        for (int j = 0; j < 4; ++j) {
            const int n = n0 + (tx << 2) + j;
            out[(((size_t)bb * NH + h) * S + sr) * DK + (n & 63)] = acc[i][j] + bias[n];
        }
    }
}

// One block per (b, h, 8 q-rows). Full score rows in LDS; two softmaxes; PV.
__global__ __launch_bounds__(256) void attn_kernel(
    const float* __restrict__ qw, const float* __restrict__ kw,
    const float* __restrict__ vw, float* __restrict__ out)
{
    __shared__ float ss[ROWS][S];       // 32 KB score rows
    __shared__ float ks[64][65];        // 16.6 KB k/v tile (pad -> conflict-free)
    __shared__ float qs[ROWS][DK];      // 2 KB

    const int t    = threadIdx.x;
    const int lane = t & 63;
    const int w    = t >> 6;            // wave id 0..3
    const int qb   = blockIdx.x;        // 0..127
    const int h    = blockIdx.y;
    const int b    = blockIdx.z;
    const int bh   = b * NH + h;
    const size_t base = (size_t)bh * S * DK;
    const float* __restrict__ qp = qw + base;
    const float* __restrict__ kp = kw + base;
    const float* __restrict__ vp = vw + base;
    const int q0 = qb * ROWS;

    // stage q rows
#pragma unroll
    for (int p = 0; p < ROWS * DK / 256; ++p) {
        int idx = t + 256 * p;
        qs[idx >> 6][idx & 63] = qp[(size_t)q0 * DK + idx];
    }

    // ---- scores: s = q.k / 8 ----
    const int j  = lane;   // key within tile
    const int r0 = w;      // rows r0 and r0+4
    for (int kt = 0; kt < S; kt += 64) {
#pragma unroll
        for (int p = 0; p < 16; ++p) {
            int idx = t + 256 * p;
            ks[idx >> 6][idx & 63] = kp[(size_t)kt * DK + idx];
        }
        __syncthreads();
        float a0 = 0.f, a1 = 0.f;
#pragma unroll 16
        for (int d = 0; d < DK; ++d) {
            float kv = ks[j][d];
            a0 += qs[r0][d] * kv;
            a1 += qs[r0 + 4][d] * kv;
        }
        ss[r0][kt + j]     = a0 * 0.125f;
        ss[r0 + 4][kt + j] = a1 * 0.125f;
        __syncthreads();
    }

    // ---- per-row: sharp softmax -> mask -> final softmax (in place) ----
    for (int rr = w; rr < ROWS; rr += 4) {
        float mx = -3.4e38f;
#pragma unroll
        for (int p = 0; p < S / 64; ++p)
            mx = fmaxf(mx, ss[rr][lane + 64 * p]);
        mx = wave_max(mx);

        float zs = 0.f;
#pragma unroll
        for (int p = 0; p < S / 64; ++p)
            zs += __expf(100.f * (ss[rr][lane + 64 * p] - mx));
        zs = wave_sum(zs);

        // does the max element itself survive? (attn_sharp_max = 1/zs)
        const bool any = !((1.0f / zs) < THRESH);
        const float m2 = any ? mx : NEG_INF;

        float z2 = 0.f;
#pragma unroll
        for (int p = 0; p < S / 64; ++p) {
            float x = ss[rr][lane + 64 * p];
            float e = __expf(100.f * (x - mx));
            bool keep = !((e / zs) < THRESH);        // exactly the reference comparison
            float sp = keep ? x : NEG_INF;
            float e2 = __expf(sp - m2);              // all-masked row -> exp(0)=1 -> uniform
            z2 += e2;
            ss[rr][lane + 64 * p] = e2;
        }
        z2 = wave_sum(z2);
        const float inv = 1.0f / z2;
#pragma unroll
        for (int p = 0; p < S / 64; ++p)
            ss[rr][lane + 64 * p] *= inv;
    }
    __syncthreads();

    // ---- PV: ctx[r][d] = sum_k attn[r][k] * v[k][d] ----
    const int d = lane;
    float c0 = 0.f, c1 = 0.f;
    for (int kt = 0; kt < S; kt += 64) {
#pragma unroll
        for (int p = 0; p < 16; ++p) {
            int idx = t + 256 * p;
            ks[idx >> 6][idx & 63] = vp[(size_t)kt * DK + idx];
        }
        __syncthreads();
#pragma unroll 16
        for (int jj = 0; jj < 64; ++jj) {
            float vv = ks[jj][d];
            c0 += ss[r0][kt + jj] * vv;
            c1 += ss[r0 + 4][kt + jj] * vv;
        }
        __syncthreads();
    }
    out[((size_t)b * S + q0 + r0) * D + h * DK + d]       = c0;
    out[((size_t)b * S + q0 + r0 + 4) * D + h * DK + d]   = c1;
}

extern "C" void kernel_launch(void* const* d_in, const int* in_sizes, int n_in,
                              void* d_out, int out_size, void* d_ws, size_t ws_size,
                              hipStream_t stream) {
    const float* Qi = (const float*)d_in[1];
    const float* Ki = (const float*)d_in[2];
    const float* Vi = (const float*)d_in[3];
    const float* Wq = (const float*)d_in[4];
    const float* bq = (const float*)d_in[5];
    const float* Wk = (const float*)d_in[6];
    const float* bk = (const float*)d_in[7];
    const float* Wv = (const float*)d_in[8];
    const float* bv = (const float*)d_in[9];
    float* outp = (float*)d_out;

    float* qws = (float*)d_ws;                       // [B,H,S,DK]
    float* kws = qws + (size_t)NB * NH * S * DK;
    float* vws = kws + (size_t)NB * NH * S * DK;

    dim3 g1(D / 64, (NB * S) / 64, 3);
    proj_kernel<<<g1, 256, 0, stream>>>(Qi, Ki, Vi, Wq, bq, Wk, bk, Wv, bv, qws, kws, vws);

    dim3 g2(S / ROWS, NH, NB);
    attn_kernel<<<g2, 256, 0, stream>>>(qws, kws, vws, outp);
}

// Round 2
// 1067.560 us; speedup vs baseline: 1.0853x; 1.0853x over previous
//
#include <hip/hip_runtime.h>

constexpr int D = 1024;   // d_model
constexpr int S = 1024;   // seq len
constexpr int NB = 4;     // batch
constexpr int NH = 16;    // heads
constexpr int DK = 64;    // head dim
constexpr float THRESH = 0.019f;
constexpr float NEG_INF = -1e9f;
constexpr int ROWS = 8;   // q-rows per attention block
constexpr int SSP = 1028; // padded score row (multiple of 4 for b128)

__device__ __forceinline__ float wave_max(float v) {
#pragma unroll
    for (int off = 32; off >= 1; off >>= 1)
        v = fmaxf(v, __shfl_xor(v, off, 64));
    return v;
}
__device__ __forceinline__ float wave_sum(float v) {
#pragma unroll
    for (int off = 32; off >= 1; off >>= 1)
        v += __shfl_xor(v, off, 64);
    return v;
}

// Y[m][n] = sum_k X[m][k] * W[n][k] + bias[n], written head-split to out[B,H,S,DK]
__global__ __launch_bounds__(256) void proj_kernel(
    const float* __restrict__ Qi, const float* __restrict__ Ki, const float* __restrict__ Vi,
    const float* __restrict__ Wq, const float* __restrict__ bq,
    const float* __restrict__ Wk, const float* __restrict__ bk,
    const float* __restrict__ Wv, const float* __restrict__ bv,
    float* __restrict__ qo, float* __restrict__ ko, float* __restrict__ vo)
{
    const int pz = blockIdx.z;
    const float* __restrict__ X    = (pz == 0) ? Qi : (pz == 1) ? Ki : Vi;
    const float* __restrict__ W    = (pz == 0) ? Wq : (pz == 1) ? Wk : Wv;
    const float* __restrict__ bias = (pz == 0) ? bq : (pz == 1) ? bk : bv;
    float* __restrict__ out        = (pz == 0) ? qo : (pz == 1) ? ko : vo;

    __shared__ __align__(16) float As[16][68];
    __shared__ __align__(16) float Bs[16][68];

    const int t  = threadIdx.x;
    const int tx = t & 15;
    const int ty = t >> 4;
    const int m0 = blockIdx.y * 64;
    const int n0 = blockIdx.x * 64;
    const int lr = t >> 2;          // 0..63 tile row
    const int lk = (t & 3) << 2;    // 0,4,8,12

    float acc[4][4] = {};

    for (int k0 = 0; k0 < D; k0 += 16) {
        float4 av  = *(const float4*)&X[(size_t)(m0 + lr) * D + k0 + lk];
        float4 bv4 = *(const float4*)&W[(size_t)(n0 + lr) * D + k0 + lk];
        As[lk + 0][lr] = av.x;  As[lk + 1][lr] = av.y;  As[lk + 2][lr] = av.z;  As[lk + 3][lr] = av.w;
        Bs[lk + 0][lr] = bv4.x; Bs[lk + 1][lr] = bv4.y; Bs[lk + 2][lr] = bv4.z; Bs[lk + 3][lr] = bv4.w;
        __syncthreads();
#pragma unroll
        for (int kk = 0; kk < 16; ++kk) {
            float4 a  = *(const float4*)&As[kk][ty << 2];
            float4 bb = *(const float4*)&Bs[kk][tx << 2];
            float a4[4] = {a.x, a.y, a.z, a.w};
            float b4[4] = {bb.x, bb.y, bb.z, bb.w};
#pragma unroll
            for (int i = 0; i < 4; ++i)
#pragma unroll
                for (int j = 0; j < 4; ++j)
                    acc[i][j] += a4[i] * b4[j];
        }
        __syncthreads();
    }

    const int h = n0 >> 6;  // head is constant per block (n-tile = 64 = DK)
#pragma unroll
    for (int i = 0; i < 4; ++i) {
        const int m  = m0 + (ty << 2) + i;
        const int bb = m >> 10;
        const int sr = m & 1023;
#pragma unroll
        for (int j = 0; j < 4; ++j) {
            const int n = n0 + (tx << 2) + j;
            out[(((size_t)bb * NH + h) * S + sr) * DK + (n & 63)] = acc[i][j] + bias[n];
        }
    }
}

// One block per (b, h, 8 q-rows). Register-blocked QK (keys in VGPRs) and PV.
__global__ __launch_bounds__(256) void attn_kernel(
    const float* __restrict__ qw, const float* __restrict__ kw,
    const float* __restrict__ vw, float* __restrict__ out)
{
    __shared__ __align__(16) float ss[ROWS][SSP];   // 32.9 KB score/attn rows
    __shared__ __align__(16) float vt[64][68];      // 17.4 KB v tile (also reduction scratch)
    __shared__ __align__(16) float qT[DK][ROWS];    //  2.0 KB q transposed, pre-scaled by 1/8

    const int t    = threadIdx.x;
    const int lane = t & 63;
    const int w    = t >> 6;
    const int h    = blockIdx.y;
    const int b    = blockIdx.z;
    const size_t base = ((size_t)b * NH + h) * S * DK;
    const float* __restrict__ qp = qw + base;
    const float* __restrict__ kp = kw + base;
    const float* __restrict__ vp = vw + base;
    const int q0 = blockIdx.x * ROWS;

    // ---- stage qT[d][r] = q[q0+r][d] / 8 ----
#pragma unroll
    for (int p = 0; p < 2; ++p) {
        int e = t + 256 * p;           // 0..511
        int d = e >> 3, r = e & 7;
        qT[d][r] = qp[(size_t)(q0 + r) * DK + d] * 0.125f;
    }
    __syncthreads();

    // ---- QK: thread owns keys 4t..4t+3 (registers), all 8 rows ----
    float accf[ROWS][4] = {};          // [row][key]
    const float* __restrict__ kbase = kp + (size_t)(4 * t) * DK;

    float4 kreg[2][4][2];              // [buf][key][half-of-8-d]
#pragma unroll
    for (int i = 0; i < 4; ++i) {
        kreg[0][i][0] = *(const float4*)&kbase[i * DK + 0];
        kreg[0][i][1] = *(const float4*)&kbase[i * DK + 4];
    }
#pragma unroll
    for (int dc = 0; dc < 8; ++dc) {
        const int cur = dc & 1, nxt = cur ^ 1;
        if (dc < 7) {
#pragma unroll
            for (int i = 0; i < 4; ++i) {
                kreg[nxt][i][0] = *(const float4*)&kbase[i * DK + (dc + 1) * 8];
                kreg[nxt][i][1] = *(const float4*)&kbase[i * DK + (dc + 1) * 8 + 4];
            }
        }
#pragma unroll
        for (int dd = 0; dd < 8; ++dd) {
            const int d = dc * 8 + dd;
            float4 qa = *(const float4*)&qT[d][0];   // rows 0..3 (broadcast)
            float4 qb = *(const float4*)&qT[d][4];   // rows 4..7
            float qr[8] = {qa.x, qa.y, qa.z, qa.w, qb.x, qb.y, qb.z, qb.w};
#pragma unroll
            for (int i = 0; i < 4; ++i) {
                const float4 kh = kreg[cur][i][dd >> 2];
                const float kv = (dd & 3) == 0 ? kh.x : (dd & 3) == 1 ? kh.y
                               : (dd & 3) == 2 ? kh.z : kh.w;
#pragma unroll
                for (int r = 0; r < ROWS; ++r)
                    accf[r][i] += qr[r] * kv;
            }
        }
    }
#pragma unroll
    for (int r = 0; r < ROWS; ++r)
        *(float4*)&ss[r][4 * t] = make_float4(accf[r][0], accf[r][1], accf[r][2], accf[r][3]);
    __syncthreads();

    // ---- per-row: sharp softmax -> mask -> final softmax (in place) ----
    for (int rr = w; rr < ROWS; rr += 4) {
        float mx = -3.4e38f;
#pragma unroll
        for (int p = 0; p < S / 64; ++p)
            mx = fmaxf(mx, ss[rr][lane + 64 * p]);
        mx = wave_max(mx);

        float zs = 0.f;
#pragma unroll
        for (int p = 0; p < S / 64; ++p)
            zs += __expf(100.f * (ss[rr][lane + 64 * p] - mx));
        zs = wave_sum(zs);

        const bool any = !((1.0f / zs) < THRESH);
        const float m2 = any ? mx : NEG_INF;

        float z2 = 0.f;
#pragma unroll
        for (int p = 0; p < S / 64; ++p) {
            float x = ss[rr][lane + 64 * p];
            float e = __expf(100.f * (x - mx));
            bool keep = !((e / zs) < THRESH);        // exactly the reference comparison
            float sp = keep ? x : NEG_INF;
            float e2 = __expf(sp - m2);              // all-masked row -> uniform
            z2 += e2;
            ss[rr][lane + 64 * p] = e2;
        }
        z2 = wave_sum(z2);
        const float inv = 1.0f / z2;
#pragma unroll
        for (int p = 0; p < S / 64; ++p)
            ss[rr][lane + 64 * p] *= inv;
    }
    __syncthreads();

    // ---- PV: thread = (rg: 4 rows, ksp: 1/8 of keys, dq: 4 d-cols) ----
    const int dq  = t & 15;            // d = 4*dq
    const int ksp = (t >> 4) & 7;      // key split 0..7
    const int rg  = t >> 7;            // rows 4rg..4rg+3
    float pacc[4][4] = {};             // [row][d]

    for (int kt0 = 0; kt0 < S; kt0 += 64) {
        {   // stage v tile: thread loads one 16-float segment of one key row
            const int key = t >> 2, dseg = (t & 3) * 16;
            const float* vr = vp + (size_t)(kt0 + key) * DK + dseg;
            float4 a = *(const float4*)(vr + 0);
            float4 c = *(const float4*)(vr + 4);
            float4 e = *(const float4*)(vr + 8);
            float4 g = *(const float4*)(vr + 12);
            *(float4*)&vt[key][dseg + 0]  = a;
            *(float4*)&vt[key][dseg + 4]  = c;
            *(float4*)&vt[key][dseg + 8]  = e;
            *(float4*)&vt[key][dseg + 12] = g;
        }
        __syncthreads();
#pragma unroll
        for (int g = 0; g < 8; g += 4) {
            const int j0 = ksp * 8 + g;            // keys j0..j0+3 in tile
            float4 at0 = *(const float4*)&ss[4 * rg + 0][kt0 + j0];
            float4 at1 = *(const float4*)&ss[4 * rg + 1][kt0 + j0];
            float4 at2 = *(const float4*)&ss[4 * rg + 2][kt0 + j0];
            float4 at3 = *(const float4*)&ss[4 * rg + 3][kt0 + j0];
            float ar[4][4] = {{at0.x, at0.y, at0.z, at0.w},
                              {at1.x, at1.y, at1.z, at1.w},
                              {at2.x, at2.y, at2.z, at2.w},
                              {at3.x, at3.y, at3.z, at3.w}};
#pragma unroll
            for (int kk = 0; kk < 4; ++kk) {
                float4 vv = *(const float4*)&vt[j0 + kk][4 * dq];
                float v4[4] = {vv.x, vv.y, vv.z, vv.w};
#pragma unroll
                for (int i = 0; i < 4; ++i)
#pragma unroll
                    for (int jd = 0; jd < 4; ++jd)
                        pacc[i][jd] += ar[i][kk] * v4[jd];
            }
        }
        __syncthreads();
    }

    // ---- reduce the 8-way key split through LDS (reuse vt) ----
    float* red = &vt[0][0];            // [ksp][r][64] = 16 KB
#pragma unroll
    for (int i = 0; i < 4; ++i)
        *(float4*)&red[ksp * 512 + (4 * rg + i) * 64 + 4 * dq] =
            make_float4(pacc[i][0], pacc[i][1], pacc[i][2], pacc[i][3]);
    __syncthreads();
#pragma unroll
    for (int p = 0; p < 2; ++p) {
        const int e = t + 256 * p;     // 0..511
        const int r = e >> 6, d = e & 63;
        float s = 0.f;
#pragma unroll
        for (int ks = 0; ks < 8; ++ks)
            s += red[ks * 512 + r * 64 + d];
        out[((size_t)b * S + q0 + r) * D + h * DK + d] = s;
    }
}

extern "C" void kernel_launch(void* const* d_in, const int* in_sizes, int n_in,
                              void* d_out, int out_size, void* d_ws, size_t ws_size,
                              hipStream_t stream) {
    const float* Qi = (const float*)d_in[1];
    const float* Ki = (const float*)d_in[2];
    const float* Vi = (const float*)d_in[3];
    const float* Wq = (const float*)d_in[4];
    const float* bq = (const float*)d_in[5];
    const float* Wk = (const float*)d_in[6];
    const float* bk = (const float*)d_in[7];
    const float* Wv = (const float*)d_in[8];
    const float* bv = (const float*)d_in[9];
    float* outp = (float*)d_out;

    float* qws = (float*)d_ws;                       // [B,H,S,DK]
    float* kws = qws + (size_t)NB * NH * S * DK;
    float* vws = kws + (size_t)NB * NH * S * DK;

    dim3 g1(D / 64, (NB * S) / 64, 3);
    proj_kernel<<<g1, 256, 0, stream>>>(Qi, Ki, Vi, Wq, bq, Wk, bk, Wv, bv, qws, kws, vws);

    dim3 g2(S / ROWS, NH, NB);
    attn_kernel<<<g2, 256, 0, stream>>>(qws, kws, vws, outp);
}

// Round 3
// 842.403 us; speedup vs baseline: 1.3754x; 1.2673x over previous
//
#include <hip/hip_runtime.h>

constexpr int D = 1024;   // d_model
constexpr int S = 1024;   // seq len
constexpr int NB = 4;     // batch
constexpr int NH = 16;    // heads
constexpr int DK = 64;    // head dim
constexpr float THRESH = 0.019f;
constexpr float NEG_INF = -1e9f;
constexpr int ROWS = 8;   // q-rows per attention block
constexpr int SSP = 1028; // padded score row (multiple of 4 for b128)

__device__ __forceinline__ float wave_max(float v) {
#pragma unroll
    for (int off = 32; off >= 1; off >>= 1)
        v = fmaxf(v, __shfl_xor(v, off, 64));
    return v;
}
__device__ __forceinline__ float wave_sum(float v) {
#pragma unroll
    for (int off = 32; off >= 1; off >>= 1)
        v += __shfl_xor(v, off, 64);
    return v;
}

// Y[m][n] = sum_k X[m][k] * W[n][k] + bias[n].
// q,v written head-split [B,H,S,DK]; k written TRANSPOSED [B,H,DK,S] for
// coalesced lane-stride-16B reads in the attention QK phase.
__global__ __launch_bounds__(256) void proj_kernel(
    const float* __restrict__ Qi, const float* __restrict__ Ki, const float* __restrict__ Vi,
    const float* __restrict__ Wq, const float* __restrict__ bq,
    const float* __restrict__ Wk, const float* __restrict__ bk,
    const float* __restrict__ Wv, const float* __restrict__ bv,
    float* __restrict__ qo, float* __restrict__ ko, float* __restrict__ vo)
{
    const int pz = blockIdx.z;
    const float* __restrict__ X    = (pz == 0) ? Qi : (pz == 1) ? Ki : Vi;
    const float* __restrict__ W    = (pz == 0) ? Wq : (pz == 1) ? Wk : Wv;
    const float* __restrict__ bias = (pz == 0) ? bq : (pz == 1) ? bk : bv;
    float* __restrict__ out        = (pz == 0) ? qo : (pz == 1) ? ko : vo;

    __shared__ __align__(16) float As[16][68];
    __shared__ __align__(16) float Bs[16][68];

    const int t  = threadIdx.x;
    const int tx = t & 15;
    const int ty = t >> 4;
    const int m0 = blockIdx.y * 64;
    const int n0 = blockIdx.x * 64;
    const int lr = t >> 2;          // 0..63 tile row
    const int lk = (t & 3) << 2;    // 0,4,8,12

    float acc[4][4] = {};

    for (int k0 = 0; k0 < D; k0 += 16) {
        float4 av  = *(const float4*)&X[(size_t)(m0 + lr) * D + k0 + lk];
        float4 bv4 = *(const float4*)&W[(size_t)(n0 + lr) * D + k0 + lk];
        As[lk + 0][lr] = av.x;  As[lk + 1][lr] = av.y;  As[lk + 2][lr] = av.z;  As[lk + 3][lr] = av.w;
        Bs[lk + 0][lr] = bv4.x; Bs[lk + 1][lr] = bv4.y; Bs[lk + 2][lr] = bv4.z; Bs[lk + 3][lr] = bv4.w;
        __syncthreads();
#pragma unroll
        for (int kk = 0; kk < 16; ++kk) {
            float4 a  = *(const float4*)&As[kk][ty << 2];
            float4 bb = *(const float4*)&Bs[kk][tx << 2];
            float a4[4] = {a.x, a.y, a.z, a.w};
            float b4[4] = {bb.x, bb.y, bb.z, bb.w};
#pragma unroll
            for (int i = 0; i < 4; ++i)
#pragma unroll
                for (int j = 0; j < 4; ++j)
                    acc[i][j] += a4[i] * b4[j];
        }
        __syncthreads();
    }

    const int h  = n0 >> 6;          // head is constant per block (n-tile = 64 = DK)
    const int bb2 = m0 >> 10;        // batch (m0 multiple of 64, block stays in one b)
    if (pz == 1) {
        // kT[((b*NH+h)*DK + d)*S + s], vectorized f4 along s
        const int s0 = (m0 & 1023) + (ty << 2);
#pragma unroll
        for (int j = 0; j < 4; ++j) {
            const int d = (tx << 2) + j;
            const float bj = bias[n0 + d];
            float4 wv = make_float4(acc[0][j] + bj, acc[1][j] + bj,
                                    acc[2][j] + bj, acc[3][j] + bj);
            *(float4*)&out[(((size_t)bb2 * NH + h) * DK + d) * S + s0] = wv;
        }
    } else {
#pragma unroll
        for (int i = 0; i < 4; ++i) {
            const int m  = m0 + (ty << 2) + i;
            const int sr = m & 1023;
#pragma unroll
            for (int j = 0; j < 4; ++j) {
                const int n = n0 + (tx << 2) + j;
                out[(((size_t)bb2 * NH + h) * S + sr) * DK + (n & 63)] = acc[i][j] + bias[n];
            }
        }
    }
}

// One block per (b, h, 8 q-rows). QK: keys in VGPRs fed by coalesced kT loads.
__global__ __launch_bounds__(256) void attn_kernel(
    const float* __restrict__ qw, const float* __restrict__ kw,
    const float* __restrict__ vw, float* __restrict__ out)
{
    __shared__ __align__(16) float ss[ROWS][SSP];   // 32.9 KB score/attn rows
    __shared__ __align__(16) float vt[64][68];      // 17.4 KB v tile (also reduction scratch)
    __shared__ __align__(16) float qT[DK][ROWS];    //  2.0 KB q transposed, pre-scaled by 1/8

    const int t    = threadIdx.x;
    const int lane = t & 63;
    const int w    = t >> 6;
    const int h    = blockIdx.y;
    const int b    = blockIdx.z;
    const size_t base = ((size_t)b * NH + h) * S * DK;
    const float* __restrict__ qp = qw + base;
    const float* __restrict__ kp = kw + base;   // kT layout: [DK][S]
    const float* __restrict__ vp = vw + base;
    const int q0 = blockIdx.x * ROWS;

    // ---- stage qT[d][r] = q[q0+r][d] / 8 ----
#pragma unroll
    for (int p = 0; p < 2; ++p) {
        int e = t + 256 * p;           // 0..511
        int d = e >> 3, r = e & 7;
        qT[d][r] = qp[(size_t)(q0 + r) * DK + d] * 0.125f;
    }
    __syncthreads();

    // ---- QK: thread owns keys 4t..4t+3; kT[d][4t..4t+3] coalesced, 4-deep ring ----
    float accf[ROWS][4] = {};          // [row][key]
    const float* __restrict__ kTb = kp + 4 * t;

    float4 kbuf[4];
#pragma unroll
    for (int d = 0; d < 4; ++d)
        kbuf[d] = *(const float4*)&kTb[(size_t)d * S];

#pragma unroll
    for (int d0 = 0; d0 < DK; d0 += 4) {
        float4 kc[4] = {kbuf[0], kbuf[1], kbuf[2], kbuf[3]};
        if (d0 < DK - 4) {
#pragma unroll
            for (int d = 0; d < 4; ++d)
                kbuf[d] = *(const float4*)&kTb[(size_t)(d0 + 4 + d) * S];
        }
#pragma unroll
        for (int dd = 0; dd < 4; ++dd) {
            const int d = d0 + dd;
            float4 qa = *(const float4*)&qT[d][0];   // rows 0..3 (broadcast)
            float4 qb = *(const float4*)&qT[d][4];   // rows 4..7
            float qr[8] = {qa.x, qa.y, qa.z, qa.w, qb.x, qb.y, qb.z, qb.w};
            float k4[4] = {kc[dd].x, kc[dd].y, kc[dd].z, kc[dd].w};
#pragma unroll
            for (int r = 0; r < ROWS; ++r)
#pragma unroll
                for (int i = 0; i < 4; ++i)
                    accf[r][i] += qr[r] * k4[i];
        }
    }
#pragma unroll
    for (int r = 0; r < ROWS; ++r)
        *(float4*)&ss[r][4 * t] = make_float4(accf[r][0], accf[r][1], accf[r][2], accf[r][3]);
    __syncthreads();

    // ---- per-row: sharp softmax -> mask -> final softmax (in place) ----
    for (int rr = w; rr < ROWS; rr += 4) {
        float mx = -3.4e38f;
#pragma unroll
        for (int p = 0; p < S / 64; ++p)
            mx = fmaxf(mx, ss[rr][lane + 64 * p]);
        mx = wave_max(mx);

        float zs = 0.f;
#pragma unroll
        for (int p = 0; p < S / 64; ++p)
            zs += __expf(100.f * (ss[rr][lane + 64 * p] - mx));
        zs = wave_sum(zs);

        const bool any = !((1.0f / zs) < THRESH);
        const float m2 = any ? mx : NEG_INF;

        float z2 = 0.f;
#pragma unroll
        for (int p = 0; p < S / 64; ++p) {
            float x = ss[rr][lane + 64 * p];
            float e = __expf(100.f * (x - mx));
            bool keep = !((e / zs) < THRESH);        // exactly the reference comparison
            float sp = keep ? x : NEG_INF;
            float e2 = __expf(sp - m2);              // all-masked row -> uniform
            z2 += e2;
            ss[rr][lane + 64 * p] = e2;
        }
        z2 = wave_sum(z2);
        const float inv = 1.0f / z2;
#pragma unroll
        for (int p = 0; p < S / 64; ++p)
            ss[rr][lane + 64 * p] *= inv;
    }
    __syncthreads();

    // ---- PV: thread = (rg: 4 rows, ksp: 1/8 of keys, dq: 4 d-cols) ----
    const int dq  = t & 15;            // d = 4*dq
    const int ksp = (t >> 4) & 7;      // key split 0..7
    const int rg  = t >> 7;            // rows 4rg..4rg+3
    float pacc[4][4] = {};             // [row][d]

    for (int kt0 = 0; kt0 < S; kt0 += 64) {
        {   // stage v tile: thread loads one 16-float segment of one key row
            const int key = t >> 2, dseg = (t & 3) * 16;
            const float* vr = vp + (size_t)(kt0 + key) * DK + dseg;
            float4 a = *(const float4*)(vr + 0);
            float4 c = *(const float4*)(vr + 4);
            float4 e = *(const float4*)(vr + 8);
            float4 g = *(const float4*)(vr + 12);
            *(float4*)&vt[key][dseg + 0]  = a;
            *(float4*)&vt[key][dseg + 4]  = c;
            *(float4*)&vt[key][dseg + 8]  = e;
            *(float4*)&vt[key][dseg + 12] = g;
        }
        __syncthreads();
#pragma unroll
        for (int g = 0; g < 8; g += 4) {
            const int j0 = ksp * 8 + g;            // keys j0..j0+3 in tile
            float4 at0 = *(const float4*)&ss[4 * rg + 0][kt0 + j0];
            float4 at1 = *(const float4*)&ss[4 * rg + 1][kt0 + j0];
            float4 at2 = *(const float4*)&ss[4 * rg + 2][kt0 + j0];
            float4 at3 = *(const float4*)&ss[4 * rg + 3][kt0 + j0];
            float ar[4][4] = {{at0.x, at0.y, at0.z, at0.w},
                              {at1.x, at1.y, at1.z, at1.w},
                              {at2.x, at2.y, at2.z, at2.w},
                              {at3.x, at3.y, at3.z, at3.w}};
#pragma unroll
            for (int kk = 0; kk < 4; ++kk) {
                float4 vv = *(const float4*)&vt[j0 + kk][4 * dq];
                float v4[4] = {vv.x, vv.y, vv.z, vv.w};
#pragma unroll
                for (int i = 0; i < 4; ++i)
#pragma unroll
                    for (int jd = 0; jd < 4; ++jd)
                        pacc[i][jd] += ar[i][kk] * v4[jd];
            }
        }
        __syncthreads();
    }

    // ---- reduce the 8-way key split through LDS (reuse vt) ----
    float* red = &vt[0][0];            // [ksp][r][64] = 16 KB
#pragma unroll
    for (int i = 0; i < 4; ++i)
        *(float4*)&red[ksp * 512 + (4 * rg + i) * 64 + 4 * dq] =
            make_float4(pacc[i][0], pacc[i][1], pacc[i][2], pacc[i][3]);
    __syncthreads();
#pragma unroll
    for (int p = 0; p < 2; ++p) {
        const int e = t + 256 * p;     // 0..511
        const int r = e >> 6, d = e & 63;
        float s = 0.f;
#pragma unroll
        for (int ks = 0; ks < 8; ++ks)
            s += red[ks * 512 + r * 64 + d];
        out[((size_t)b * S + q0 + r) * D + h * DK + d] = s;
    }
}

extern "C" void kernel_launch(void* const* d_in, const int* in_sizes, int n_in,
                              void* d_out, int out_size, void* d_ws, size_t ws_size,
                              hipStream_t stream) {
    const float* Qi = (const float*)d_in[1];
    const float* Ki = (const float*)d_in[2];
    const float* Vi = (const float*)d_in[3];
    const float* Wq = (const float*)d_in[4];
    const float* bq = (const float*)d_in[5];
    const float* Wk = (const float*)d_in[6];
    const float* bk = (const float*)d_in[7];
    const float* Wv = (const float*)d_in[8];
    const float* bv = (const float*)d_in[9];
    float* outp = (float*)d_out;

    float* qws = (float*)d_ws;                       // [B,H,S,DK]
    float* kws = qws + (size_t)NB * NH * S * DK;     // [B,H,DK,S] (transposed)
    float* vws = kws + (size_t)NB * NH * S * DK;     // [B,H,S,DK]

    dim3 g1(D / 64, (NB * S) / 64, 3);
    proj_kernel<<<g1, 256, 0, stream>>>(Qi, Ki, Vi, Wq, bq, Wk, bk, Wv, bv, qws, kws, vws);

    dim3 g2(S / ROWS, NH, NB);
    attn_kernel<<<g2, 256, 0, stream>>>(qws, kws, vws, outp);
}